// Round 11
// baseline (123.212 us; speedup 1.0000x reference)
//
#include <hip/hip_runtime.h>
#include <hip/hip_bf16.h>
#include <math.h>

#define H 128
#define KN 16
#define NN 16384
#define NB 16     // nodes per block (fused)
#define EB 256    // edges per block
#define HS 136    // padded bf16 row stride for hsh/msum

typedef short s16x8 __attribute__((ext_vector_type(8)));
typedef float f32x4 __attribute__((ext_vector_type(4)));

__device__ __forceinline__ float u2f_lo(uint u){
    union { uint i; float f; } v; v.i = u << 16; return v.f;
}
__device__ __forceinline__ float u2f_hi(uint u){
    union { uint i; float f; } v; v.i = u & 0xffff0000u; return v.f;
}
__device__ __forceinline__ float b2f(ushort u){
    union { uint i; float f; } v; v.i = ((uint)u) << 16; return v.f;
}
__device__ __forceinline__ uint pk2(float lo, float hi){
    __hip_bfloat162 b = __float22bfloat162_rn(float2{lo, hi});
    uint u; __builtin_memcpy(&u, &b, 4); return u;
}
__device__ __forceinline__ ushort f2b1(float f){
    __hip_bfloat16 b = __float2bfloat16(f);
    ushort u; __builtin_memcpy(&u, &b, 2); return u;
}
__device__ __forceinline__ float silu_f(float v){
    float e = __expf(-v);
    return v * __builtin_amdgcn_rcpf(1.0f + e);
}

// ---------------------------------------------------------------------------
// Pack weights (transposed) into MFMA A-fragment order, fp32 -> bf16.
// ---------------------------------------------------------------------------
__global__ __launch_bounds__(256) void pack_all(
    const float* __restrict__ We2, const float* __restrict__ Wc1,
    const float* __restrict__ Wn1, const float* __restrict__ Wn2,
    const float* __restrict__ We1,
    ushort* __restrict__ dWe2, ushort* __restrict__ dWc1,
    ushort* __restrict__ dWn1, ushort* __restrict__ dWn2,
    ushort* __restrict__ dW1p)
{
    int idx = blockIdx.x * 256 + threadIdx.x;
    int fid = idx >> 6, l = idx & 63;
    const float* src; ushort* dst; int Kt; int mode = 0; int lfid;
    if (fid < 32)       { src = We2; dst = dWe2; Kt = 4; lfid = fid; }
    else if (fid < 64)  { src = Wc1; dst = dWc1; Kt = 4; lfid = fid - 32; }
    else if (fid < 128) { src = Wn1; dst = dWn1; Kt = 8; lfid = fid - 64; }
    else if (fid < 160) { src = Wn2; dst = dWn2; Kt = 4; lfid = fid - 128; }
    else                { src = We1; dst = dW1p; Kt = 4; mode = 1; lfid = fid - 160; }
    int mt = lfid / Kt, kt = lfid % Kt;
    int m = mt * 16 + (l & 15);
    s16x8 ov;
#pragma unroll
    for (int e = 0; e < 8; e++){
        int k = kt * 32 + ((l >> 4) << 3) + e;
        float v;
        if (mode == 0) v = src[k * 128 + m];
        else           v = src[(k + ((m >= 128) ? 128 : 0)) * 128 + (m & 127)];
        ov[e] = (short)f2b1(v);
    }
    *(s16x8*)(dst + (size_t)lfid * 512 + l * 8) = ov;
}

// ---------------------------------------------------------------------------
// Precompute A[i][c] = h[i]@We1[:128] + be1,  Bm[i][c] = h[i]@We1[128:256]
// ---------------------------------------------------------------------------
__global__ __launch_bounds__(256) void precompute_mfma(
    const float* __restrict__ h, const float* __restrict__ be1,
    const ushort* __restrict__ W1p,
    ushort* __restrict__ A, ushort* __restrict__ Bm)
{
    const int tid = threadIdx.x;
    const int w = tid >> 6, l = tid & 63, lg = l >> 4, li = l & 15;
    const int i0 = blockIdx.x * 64;

    f32x4 acc[4][4];
#pragma unroll
    for (int a = 0; a < 4; a++)
#pragma unroll
        for (int b = 0; b < 4; b++){ acc[a][b][0]=0.f; acc[a][b][1]=0.f; acc[a][b][2]=0.f; acc[a][b][3]=0.f; }

    for (int nt = 0; nt < 4; nt++){
        int node = i0 + nt * 16 + li;
        const float* hp = h + (size_t)node * 128 + lg * 8;
        s16x8 bfr[4];
#pragma unroll
        for (int kt = 0; kt < 4; kt++){
            float4 v0 = *(const float4*)(hp + kt * 32);
            float4 v1 = *(const float4*)(hp + kt * 32 + 4);
            uint4 uu = make_uint4(pk2(v0.x, v0.y), pk2(v0.z, v0.w),
                                  pk2(v1.x, v1.y), pk2(v1.z, v1.w));
            s16x8 bf; __builtin_memcpy(&bf, &uu, 16);
            bfr[kt] = bf;
        }
#pragma unroll
        for (int mtl = 0; mtl < 4; mtl++){
            int mt = w * 4 + mtl;
#pragma unroll
            for (int kt = 0; kt < 4; kt++){
                s16x8 af = *(const s16x8*)(W1p + (size_t)(mt * 4 + kt) * 512 + l * 8);
                acc[mtl][nt] = __builtin_amdgcn_mfma_f32_16x16x32_bf16(af, bfr[kt], acc[mtl][nt], 0, 0, 0);
            }
        }
    }
#pragma unroll
    for (int mtl = 0; mtl < 4; mtl++){
        int mt = w * 4 + mtl;
        int ccb = mt * 16 + lg * 4;
#pragma unroll
        for (int nt = 0; nt < 4; nt++){
            int node = i0 + nt * 16 + li;
            float b0=0.f,b1=0.f,b2=0.f,b3=0.f;
            if (ccb < 128){ float4 bb = *(const float4*)(be1 + ccb); b0=bb.x; b1=bb.y; b2=bb.z; b3=bb.w; }
            uint2 val = make_uint2(pk2(acc[mtl][nt][0] + b0, acc[mtl][nt][1] + b1),
                                   pk2(acc[mtl][nt][2] + b2, acc[mtl][nt][3] + b3));
            ushort* dst = (ccb < 128) ? (A + (size_t)node * 128 + ccb)
                                      : (Bm + (size_t)node * 128 + (ccb - 128));
            *(uint2*)dst = val;
        }
    }
}

// ---------------------------------------------------------------------------
// GEMM helpers: 32 output cols (wave-colgroup w4) x 64 edges / pass, on a
// 128-row half-tile (mbase points at the half's first row).
// ---------------------------------------------------------------------------
__device__ __forceinline__ void gemm_pass(
    const ushort* mbase, const ushort* __restrict__ WT,
    int nt0, int w4, int l, int lg, int li, f32x4 acc[2][4])
{
#pragma unroll
    for (int kt = 0; kt < 4; kt++){
        s16x8 bfr[4];
#pragma unroll
        for (int n = 0; n < 4; n++){
            int el = (nt0 + n) * 16 + li;
            int blk = (kt * 4 + lg) ^ (el & 7);
            bfr[n] = *(const s16x8*)&mbase[el * 128 + blk * 8];
        }
#pragma unroll
        for (int mtl = 0; mtl < 2; mtl++){
            s16x8 af = *(const s16x8*)&WT[(size_t)((w4 * 2 + mtl) * 4 + kt) * 512 + l * 8];
#pragma unroll
            for (int n = 0; n < 4; n++)
                acc[mtl][n] = __builtin_amdgcn_mfma_f32_16x16x32_bf16(af, bfr[n], acc[mtl][n], 0, 0, 0);
        }
    }
}

__device__ __forceinline__ void m_epi(
    ushort* mbase, const float* __restrict__ be2,
    int nt0, int w4, int lg, int li, f32x4 acc[2][4])
{
#pragma unroll
    for (int mtl = 0; mtl < 2; mtl++){
        int mt = w4 * 2 + mtl;
        int cb = mt * 16 + lg * 4;
        float4 bb = *(const float4*)&be2[cb];
#pragma unroll
        for (int n = 0; n < 4; n++){
            int el = (nt0 + n) * 16 + li;
            f32x4 a = acc[mtl][n];
            uint2 val = make_uint2(pk2(silu_f(a[0] + bb.x), silu_f(a[1] + bb.y)),
                                   pk2(silu_f(a[2] + bb.z), silu_f(a[3] + bb.w)));
            int blk = (mt * 2 + (lg >> 1)) ^ (el & 7);
            *(uint2*)&mbase[el * 128 + blk * 8 + (lg & 1) * 4] = val;
        }
    }
}

__device__ __forceinline__ void gemm2_pass(
    const ushort* mbase, const ushort* __restrict__ WT,
    const float* __restrict__ bc1, const float* __restrict__ Wc2,
    int nt0, int w4, int l, int lg, int li, float cwp[4])
{
    f32x4 acc[2][4];
#pragma unroll
    for (int m = 0; m < 2; m++)
#pragma unroll
        for (int n = 0; n < 4; n++){ acc[m][n][0]=0.f; acc[m][n][1]=0.f; acc[m][n][2]=0.f; acc[m][n][3]=0.f; }

    __builtin_amdgcn_s_setprio(1);
    gemm_pass(mbase, WT, nt0, w4, l, lg, li, acc);
    __builtin_amdgcn_s_setprio(0);

    cwp[0]=0.f; cwp[1]=0.f; cwp[2]=0.f; cwp[3]=0.f;
#pragma unroll
    for (int mtl = 0; mtl < 2; mtl++){
        int cb = (w4 * 2 + mtl) * 16 + lg * 4;
        float4 bc = *(const float4*)&bc1[cb];
        float4 wc = *(const float4*)&Wc2[cb];
#pragma unroll
        for (int n = 0; n < 4; n++){
            f32x4 a = acc[mtl][n];
            cwp[n] += silu_f(a[0] + bc.x) * wc.x + silu_f(a[1] + bc.y) * wc.y
                    + silu_f(a[2] + bc.z) * wc.z + silu_f(a[3] + bc.w) * wc.w;
        }
    }
#pragma unroll
    for (int n = 0; n < 4; n++){
        cwp[n] += __shfl_xor(cwp[n], 16);
        cwp[n] += __shfl_xor(cwp[n], 32);
    }
}

// ---------------------------------------------------------------------------
// Fused edge + node kernel. 16 nodes / 256 edges per block, 512 threads
// (8 waves: w4 = colgroup, half = edge half). LDS 81152 B -> 2 blocks/CU.
// ---------------------------------------------------------------------------
__global__ __launch_bounds__(512, 4) void egnn_fused(
    const float* __restrict__ h, const float* __restrict__ x,
    const int* __restrict__ edge_idx,
    const ushort* __restrict__ A, const ushort* __restrict__ Bm,
    const float* __restrict__ We1,
    const ushort* __restrict__ We2T, const float* __restrict__ be2,
    const ushort* __restrict__ Wc1T, const float* __restrict__ bc1,
    const float* __restrict__ Wc2,
    const ushort* __restrict__ Wn1T, const float* __restrict__ bn1,
    const ushort* __restrict__ Wn2T, const float* __restrict__ bn2,
    float* __restrict__ out, int BN)
{
    // m_lds: t then m (256x128 bf16). After GEMM2: rows 0..15 = u, rows 16..31 = cwv4.
    __shared__ __align__(16) ushort m_lds[EB * 128];   // 65536
    __shared__ __align__(16) float  unionBuf[2048];    // 8192: Ashf(16x128 f32) -> msum_bf overlay
    __shared__ __align__(16) ushort hsh_bf[NB * HS];   // 4352
    __shared__ float  sqd[EB];                         // 1024
    __shared__ ushort xdb[EB * 3];                     // 1536
    __shared__ ushort jgs[EB];                         // 512   => 81152

    float* Ashf = unionBuf;                            // [P0..P1]
    ushort* msum_bf = (ushort*)unionBuf;               // [post-GEMM1..GEMM3]
    float* cwv4 = (float*)(m_lds + 2048);              // bytes 4096..8191, [post-[5]..x-upd]

    const int tid = threadIdx.x;
    const int w = tid >> 6, l = tid & 63, lg = l >> 4, li = l & 15;
    const int w4 = w & 3, half = w >> 2;
    const int ebase = half * 128;

    // XCD-chunked swizzle
    int nwg = gridDim.x;
    int per_xcd = nwg >> 3;
    int phys = blockIdx.x;
    int group = (phys & 7) * per_xcd + (phys >> 3);
    const int i0 = group * NB;

    ushort* mhalf = m_lds + ebase * 128;

    // ---- P0: stage h(bf16), A(fp32), geometry ----
    {
        int r = tid >> 5, c = (tid & 31) * 4;          // r 0..15
        float4 hv = *(const float4*)&h[(size_t)(i0 + r) * 128 + c];
        *(uint2*)&hsh_bf[r * HS + c] = make_uint2(pk2(hv.x, hv.y), pk2(hv.z, hv.w));
        uint2 av = *(const uint2*)&A[(size_t)(i0 + r) * 128 + c];
        float4 af;
        af.x = u2f_lo(av.x); af.y = u2f_hi(av.x);
        af.z = u2f_lo(av.y); af.w = u2f_hi(av.y);
        *(float4*)&Ashf[r * 128 + c] = af;
    }
    if (tid < EB){
        int e = tid;
        int i = i0 + (e >> 4);
        int b = i / NN;
        int jl = edge_idx[(size_t)i * KN + (e & 15)];
        int j = b * NN + jl;
        jgs[e] = (ushort)j;
        float d0 = x[(size_t)i*3+0] - x[(size_t)j*3+0];
        float d1 = x[(size_t)i*3+1] - x[(size_t)j*3+1];
        float d2 = x[(size_t)i*3+2] - x[(size_t)j*3+2];
        xdb[e*3+0] = f2b1(d0); xdb[e*3+1] = f2b1(d1); xdb[e*3+2] = f2b1(d2);
        sqd[e] = d0*d0 + d1*d1 + d2*d2;
    }
    __syncthreads();   // [0]

    // ---- P1: t = silu(A[i] + Bm[j] + sqd*We1[256]) -> m_lds (bf16, swizzled)
    //      wave w owns edges [32w, 32w+32)
    {
        const float* w256 = We1 + 256 * 128;
#pragma unroll
        for (int nt = 0; nt < 2; nt++){
            int edge = w * 32 + nt * 16 + li;
            int nodel = edge >> 4;
            int j = jgs[edge];
            float sq = sqd[edge];
#pragma unroll
            for (int kt = 0; kt < 4; kt++){
                int c8 = kt * 32 + lg * 8;
                uint4 ub = *(const uint4*)&Bm[(size_t)j * 128 + c8];
                float4 a0 = *(const float4*)&Ashf[nodel * 128 + c8];
                float4 a1 = *(const float4*)&Ashf[nodel * 128 + c8 + 4];
                float4 w0 = *(const float4*)&w256[c8];
                float4 w1 = *(const float4*)&w256[c8 + 4];
                float alo[4] = {a0.x, a0.z, a1.x, a1.z};
                float ahi[4] = {a0.y, a0.w, a1.y, a1.w};
                float wlo[4] = {w0.x, w0.z, w1.x, w1.z};
                float whi[4] = {w0.y, w0.w, w1.y, w1.w};
                const uint* pb = (const uint*)&ub;
                uint ov[4];
#pragma unroll
                for (int p = 0; p < 4; p++){
                    float tlo = fmaf(sq, wlo[p], alo[p] + u2f_lo(pb[p]));
                    float thi = fmaf(sq, whi[p], ahi[p] + u2f_hi(pb[p]));
                    ov[p] = pk2(silu_f(tlo), silu_f(thi));
                }
                int blk = (kt * 4 + lg) ^ (edge & 7);
                *(uint4*)&m_lds[edge * 128 + blk * 8] = make_uint4(ov[0], ov[1], ov[2], ov[3]);
            }
        }
    }
    __syncthreads();   // [1] t complete; Ashf dead

    // ---- GEMM1 pass A: own half, edges 0..63 ----
    {
        f32x4 acc[2][4];
#pragma unroll
        for (int m = 0; m < 2; m++)
#pragma unroll
            for (int n = 0; n < 4; n++){ acc[m][n][0]=0.f; acc[m][n][1]=0.f; acc[m][n][2]=0.f; acc[m][n][3]=0.f; }
        __builtin_amdgcn_s_setprio(1);
        gemm_pass(mhalf, We2T, 0, w4, l, lg, li, acc);
        __builtin_amdgcn_s_setprio(0);
        __syncthreads();   // [2] all waves done reading their half's t rows 0..63
        m_epi(mhalf, be2, 0, w4, lg, li, acc);
    }
    // ---- GEMM1 pass B: own half, edges 64..127 ----
    {
        f32x4 acc[2][4];
#pragma unroll
        for (int m = 0; m < 2; m++)
#pragma unroll
            for (int n = 0; n < 4; n++){ acc[m][n][0]=0.f; acc[m][n][1]=0.f; acc[m][n][2]=0.f; acc[m][n][3]=0.f; }
        __builtin_amdgcn_s_setprio(1);
        gemm_pass(mhalf, We2T, 4, w4, l, lg, li, acc);
        __builtin_amdgcn_s_setprio(0);
        __syncthreads();   // [3]
        m_epi(mhalf, be2, 4, w4, lg, li, acc);
    }

    // ---- msum: own half's 8 nodes, own cols (own-wave data; lgkm only) ----
    {
        int nd = half * 8 + (l >> 3);
        int c0 = w4 * 32 + (l & 7) * 4;
        float s0=0.f, s1=0.f, s2=0.f, s3=0.f;
#pragma unroll
        for (int s = 0; s < 16; s++){
            int k = (s + (l >> 3)) & 15;
            int edge = nd * 16 + k;
            int blk = (c0 >> 3) ^ (edge & 7);
            uint2 v = *(const uint2*)&m_lds[edge * 128 + blk * 8 + (c0 & 4)];
            s0 += u2f_lo(v.x); s1 += u2f_hi(v.x);
            s2 += u2f_lo(v.y); s3 += u2f_hi(v.y);
        }
        *(uint2*)&msum_bf[nd * HS + c0] = make_uint2(pk2(s0, s1), pk2(s2, s3));
    }
    __syncthreads();   // [4] m + msum complete

    // ---- GEMM2 (two passes): cw partials kept in registers ----
    float cwpA[4], cwpB[4];
    gemm2_pass(mhalf, Wc1T, bc1, Wc2, 0, w4, l, lg, li, cwpA);
    gemm2_pass(mhalf, Wc1T, bc1, Wc2, 4, w4, l, lg, li, cwpB);
    __syncthreads();   // [5] all waves done reading m; rows 0..31 reusable

    // ---- cwv write (rows 16..31 region) ----
    if (lg == 0){
#pragma unroll
        for (int n = 0; n < 4; n++){
            cwv4[w4 * EB + ebase + n * 16 + li]      = cwpA[n];
            cwv4[w4 * EB + ebase + 64 + n * 16 + li] = cwpB[n];
        }
    }

    // ---- GEMM3 (waves 0..3): u = silu([h|msum]@Wn1+bn1) -> m_lds rows 0..15 ----
    if (w < 4){
        f32x4 acc3[2];
        acc3[0][0]=0.f; acc3[0][1]=0.f; acc3[0][2]=0.f; acc3[0][3]=0.f;
        acc3[1][0]=0.f; acc3[1][1]=0.f; acc3[1][2]=0.f; acc3[1][3]=0.f;
#pragma unroll
        for (int kt = 0; kt < 8; kt++){
            const ushort* bp = (kt < 4) ? &hsh_bf[li * HS + kt * 32 + lg * 8]
                                        : &msum_bf[li * HS + (kt - 4) * 32 + lg * 8];
            s16x8 bf = *(const s16x8*)bp;
#pragma unroll
            for (int mtl = 0; mtl < 2; mtl++){
                int mt = w * 2 + mtl;
                s16x8 af = *(const s16x8*)&Wn1T[(size_t)(mt * 8 + kt) * 512 + l * 8];
                acc3[mtl] = __builtin_amdgcn_mfma_f32_16x16x32_bf16(af, bf, acc3[mtl], 0, 0, 0);
            }
        }
#pragma unroll
        for (int mtl = 0; mtl < 2; mtl++){
            int mt = w * 2 + mtl;
            int cb = mt * 16 + lg * 4;
            float4 bb = *(const float4*)&bn1[cb];
            f32x4 a = acc3[mtl];
            uint o01 = pk2(silu_f(a[0] + bb.x), silu_f(a[1] + bb.y));
            uint o23 = pk2(silu_f(a[2] + bb.z), silu_f(a[3] + bb.w));
            int blk = (mt * 2 + (lg >> 1)) ^ (li & 7);
            *(uint2*)&m_lds[li * 128 + blk * 8 + (lg & 1) * 4] = make_uint2(o01, o23);
        }
    }
    __syncthreads();   // [6] u + cwv complete

    if (w < 4){
        // ---- GEMM4: h_new = u@Wn2 + bn2 + h ----
        f32x4 acc4[2];
        acc4[0][0]=0.f; acc4[0][1]=0.f; acc4[0][2]=0.f; acc4[0][3]=0.f;
        acc4[1][0]=0.f; acc4[1][1]=0.f; acc4[1][2]=0.f; acc4[1][3]=0.f;
#pragma unroll
        for (int kt = 0; kt < 4; kt++){
            int blk = (kt * 4 + lg) ^ (li & 7);
            s16x8 bf = *(const s16x8*)&m_lds[li * 128 + blk * 8];
#pragma unroll
            for (int mtl = 0; mtl < 2; mtl++){
                int mt = w * 2 + mtl;
                s16x8 af = *(const s16x8*)&Wn2T[(size_t)(mt * 4 + kt) * 512 + l * 8];
                acc4[mtl] = __builtin_amdgcn_mfma_f32_16x16x32_bf16(af, bf, acc4[mtl], 0, 0, 0);
            }
        }
#pragma unroll
        for (int mtl = 0; mtl < 2; mtl++){
            int mt = w * 2 + mtl;
            int cb = mt * 16 + lg * 4;
            float4 bb = *(const float4*)&bn2[cb];
            uint2 hu = *(const uint2*)&hsh_bf[li * HS + cb];
            f32x4 a = acc4[mtl];
            float4 o;
            o.x = a[0] + bb.x + u2f_lo(hu.x);
            o.y = a[1] + bb.y + u2f_hi(hu.x);
            o.z = a[2] + bb.z + u2f_lo(hu.y);
            o.w = a[3] + bb.w + u2f_hi(hu.y);
            *(float4*)&out[(size_t)(i0 + li) * 128 + cb] = o;
        }
    } else {
        // ---- x update (waves 4..7): 48 threads ----
        int idx = tid - 256;
        if (idx < NB * 3){
            int nd = idx / 3, d = idx % 3;
            int i = i0 + nd;
            float s = 0.f;
#pragma unroll
            for (int k = 0; k < 16; k++){
                int e = nd * 16 + k;
                float cw = cwv4[0 * EB + e] + cwv4[1 * EB + e]
                         + cwv4[2 * EB + e] + cwv4[3 * EB + e];
                s += b2f(xdb[e * 3 + d]) * cw;
            }
            out[(size_t)BN * H + (size_t)i * 3 + d] = x[(size_t)i * 3 + d] + s * (1.0f / 16.0f);
        }
    }
}

extern "C" void kernel_launch(void* const* d_in, const int* in_sizes, int n_in,
                              void* d_out, int out_size, void* d_ws, size_t ws_size,
                              hipStream_t stream) {
    const float* h        = (const float*)d_in[0];
    const float* x        = (const float*)d_in[1];
    const int*   edge_idx = (const int*)d_in[2];
    const float* We1      = (const float*)d_in[3];
    const float* be1      = (const float*)d_in[4];
    const float* We2      = (const float*)d_in[5];
    const float* be2      = (const float*)d_in[6];
    const float* Wc1      = (const float*)d_in[7];
    const float* bc1      = (const float*)d_in[8];
    const float* Wc2      = (const float*)d_in[9];
    const float* Wn1      = (const float*)d_in[10];
    const float* bn1      = (const float*)d_in[11];
    const float* Wn2      = (const float*)d_in[12];
    const float* bn2      = (const float*)d_in[13];
    float* out = (float*)d_out;

    const int BN = in_sizes[0] / H;   // 32768

    ushort* A    = (ushort*)d_ws;
    ushort* Bm   = A + (size_t)BN * H;
    ushort* We2T = Bm + (size_t)BN * H;
    ushort* Wc1T = We2T + 32 * 512;
    ushort* Wn1T = Wc1T + 32 * 512;
    ushort* Wn2T = Wn1T + 64 * 512;
    ushort* W1pT = Wn2T + 32 * 512;

    pack_all<<<56, 256, 0, stream>>>(We2, Wc1, Wn1, Wn2, We1,
                                     We2T, Wc1T, Wn1T, Wn2T, W1pT);
    precompute_mfma<<<BN / 64, 256, 0, stream>>>(h, be1, W1pT, A, Bm);
    egnn_fused<<<BN / NB, 512, 0, stream>>>(h, x, edge_idx, A, Bm, We1,
                                            We2T, be2, Wc1T, bc1, Wc2,
                                            Wn1T, bn1, Wn2T, bn2, out, BN);
}

// Round 12
// 119.604 us; speedup vs baseline: 1.0302x; 1.0302x over previous
//
#include <hip/hip_runtime.h>
#include <hip/hip_bf16.h>
#include <math.h>

#define H 128
#define KN 16
#define NN 16384
#define NB 8      // nodes per block (fused)
#define EB 128    // edges per block
#define HS 136    // padded bf16 row stride for hsh/msum

typedef short s16x8 __attribute__((ext_vector_type(8)));
typedef float f32x4 __attribute__((ext_vector_type(4)));

__device__ __forceinline__ float u2f_lo(uint u){
    union { uint i; float f; } v; v.i = u << 16; return v.f;
}
__device__ __forceinline__ float u2f_hi(uint u){
    union { uint i; float f; } v; v.i = u & 0xffff0000u; return v.f;
}
__device__ __forceinline__ float b2f(ushort u){
    union { uint i; float f; } v; v.i = ((uint)u) << 16; return v.f;
}
__device__ __forceinline__ uint pk2(float lo, float hi){
    __hip_bfloat162 b = __float22bfloat162_rn(float2{lo, hi});
    uint u; __builtin_memcpy(&u, &b, 4); return u;
}
__device__ __forceinline__ ushort f2b1(float f){
    __hip_bfloat16 b = __float2bfloat16(f);
    ushort u; __builtin_memcpy(&u, &b, 2); return u;
}
__device__ __forceinline__ float silu_f(float v){
    float e = __expf(-v);
    return v * __builtin_amdgcn_rcpf(1.0f + e);
}

// ---------------------------------------------------------------------------
// Pack weights (transposed) into MFMA A-fragment order, fp32 -> bf16.
// packed[(mt*Kt+kt)*512 + lane*8 + e] = W[k][m], k = kt*32 + 8*(lane>>4)+e,
// m = mt*16 + (lane&15).
// ---------------------------------------------------------------------------
__global__ __launch_bounds__(256) void pack_all(
    const float* __restrict__ We2, const float* __restrict__ Wc1,
    const float* __restrict__ Wn1, const float* __restrict__ Wn2,
    const float* __restrict__ We1,
    ushort* __restrict__ dWe2, ushort* __restrict__ dWc1,
    ushort* __restrict__ dWn1, ushort* __restrict__ dWn2,
    ushort* __restrict__ dW1p)
{
    int idx = blockIdx.x * 256 + threadIdx.x;
    int fid = idx >> 6, l = idx & 63;
    const float* src; ushort* dst; int Kt; int mode = 0; int lfid;
    if (fid < 32)       { src = We2; dst = dWe2; Kt = 4; lfid = fid; }
    else if (fid < 64)  { src = Wc1; dst = dWc1; Kt = 4; lfid = fid - 32; }
    else if (fid < 128) { src = Wn1; dst = dWn1; Kt = 8; lfid = fid - 64; }
    else if (fid < 160) { src = Wn2; dst = dWn2; Kt = 4; lfid = fid - 128; }
    else                { src = We1; dst = dW1p; Kt = 4; mode = 1; lfid = fid - 160; }
    int mt = lfid / Kt, kt = lfid % Kt;
    int m = mt * 16 + (l & 15);
    s16x8 ov;
#pragma unroll
    for (int e = 0; e < 8; e++){
        int k = kt * 32 + ((l >> 4) << 3) + e;
        float v;
        if (mode == 0) v = src[k * 128 + m];
        else           v = src[(k + ((m >= 128) ? 128 : 0)) * 128 + (m & 127)];
        ov[e] = (short)f2b1(v);
    }
    *(s16x8*)(dst + (size_t)lfid * 512 + l * 8) = ov;
}

// ---------------------------------------------------------------------------
// Precompute A[i][c] = h[i]@We1[:128] + be1,  Bm[i][c] = h[i]@We1[128:256]
// ---------------------------------------------------------------------------
__global__ __launch_bounds__(256) void precompute_mfma(
    const float* __restrict__ h, const float* __restrict__ be1,
    const ushort* __restrict__ W1p,
    ushort* __restrict__ A, ushort* __restrict__ Bm)
{
    const int tid = threadIdx.x;
    const int w = tid >> 6, l = tid & 63, lg = l >> 4, li = l & 15;
    const int i0 = blockIdx.x * 64;

    f32x4 acc[4][4];
#pragma unroll
    for (int a = 0; a < 4; a++)
#pragma unroll
        for (int b = 0; b < 4; b++){ acc[a][b][0]=0.f; acc[a][b][1]=0.f; acc[a][b][2]=0.f; acc[a][b][3]=0.f; }

    for (int nt = 0; nt < 4; nt++){
        int node = i0 + nt * 16 + li;
        const float* hp = h + (size_t)node * 128 + lg * 8;
        s16x8 bfr[4];
#pragma unroll
        for (int kt = 0; kt < 4; kt++){
            float4 v0 = *(const float4*)(hp + kt * 32);
            float4 v1 = *(const float4*)(hp + kt * 32 + 4);
            uint4 uu = make_uint4(pk2(v0.x, v0.y), pk2(v0.z, v0.w),
                                  pk2(v1.x, v1.y), pk2(v1.z, v1.w));
            s16x8 bf; __builtin_memcpy(&bf, &uu, 16);
            bfr[kt] = bf;
        }
#pragma unroll
        for (int mtl = 0; mtl < 4; mtl++){
            int mt = w * 4 + mtl;
#pragma unroll
            for (int kt = 0; kt < 4; kt++){
                s16x8 af = *(const s16x8*)(W1p + (size_t)(mt * 4 + kt) * 512 + l * 8);
                acc[mtl][nt] = __builtin_amdgcn_mfma_f32_16x16x32_bf16(af, bfr[kt], acc[mtl][nt], 0, 0, 0);
            }
        }
    }
#pragma unroll
    for (int mtl = 0; mtl < 4; mtl++){
        int mt = w * 4 + mtl;
        int ccb = mt * 16 + lg * 4;
#pragma unroll
        for (int nt = 0; nt < 4; nt++){
            int node = i0 + nt * 16 + li;
            float b0=0.f,b1=0.f,b2=0.f,b3=0.f;
            if (ccb < 128){ float4 bb = *(const float4*)(be1 + ccb); b0=bb.x; b1=bb.y; b2=bb.z; b3=bb.w; }
            uint2 val = make_uint2(pk2(acc[mtl][nt][0] + b0, acc[mtl][nt][1] + b1),
                                   pk2(acc[mtl][nt][2] + b2, acc[mtl][nt][3] + b3));
            ushort* dst = (ccb < 128) ? (A + (size_t)node * 128 + ccb)
                                      : (Bm + (size_t)node * 128 + (ccb - 128));
            *(uint2*)dst = val;
        }
    }
}

// ---------------------------------------------------------------------------
// GEMM helpers for the fused kernel: 32 output cols (wave) x 64 edges / pass.
// ---------------------------------------------------------------------------
__device__ __forceinline__ void gemm_pass(
    const ushort* mlds, const ushort* __restrict__ WT,
    int nt0, int w, int l, int lg, int li, f32x4 acc[2][4])
{
#pragma unroll
    for (int kt = 0; kt < 4; kt++){
        s16x8 bfr[4];
#pragma unroll
        for (int n = 0; n < 4; n++){
            int edge = (nt0 + n) * 16 + li;
            int blk = (kt * 4 + lg) ^ (edge & 7);
            bfr[n] = *(const s16x8*)&mlds[edge * 128 + blk * 8];
        }
#pragma unroll
        for (int mtl = 0; mtl < 2; mtl++){
            s16x8 af = *(const s16x8*)&WT[(size_t)((w * 2 + mtl) * 4 + kt) * 512 + l * 8];
#pragma unroll
            for (int n = 0; n < 4; n++)
                acc[mtl][n] = __builtin_amdgcn_mfma_f32_16x16x32_bf16(af, bfr[n], acc[mtl][n], 0, 0, 0);
        }
    }
}

__device__ __forceinline__ void m_epi(
    ushort* mlds, const float* __restrict__ be2,
    int nt0, int w, int lg, int li, f32x4 acc[2][4])
{
#pragma unroll
    for (int mtl = 0; mtl < 2; mtl++){
        int mt = w * 2 + mtl;
        int cb = mt * 16 + lg * 4;
        float4 bb = *(const float4*)&be2[cb];
#pragma unroll
        for (int n = 0; n < 4; n++){
            int el = (nt0 + n) * 16 + li;
            f32x4 a = acc[mtl][n];
            uint2 val = make_uint2(pk2(silu_f(a[0] + bb.x), silu_f(a[1] + bb.y)),
                                   pk2(silu_f(a[2] + bb.z), silu_f(a[3] + bb.w)));
            int blk = (mt * 2 + (lg >> 1)) ^ (el & 7);
            *(uint2*)&mlds[el * 128 + blk * 8 + (lg & 1) * 4] = val;
        }
    }
}

__device__ __forceinline__ void gemm2_pass(
    const ushort* mlds, const ushort* __restrict__ WT,
    const float* __restrict__ bc1, const float* __restrict__ Wc2,
    float* cwrow, int nt0, int w, int l, int lg, int li)
{
    f32x4 acc[2][4];
#pragma unroll
    for (int m = 0; m < 2; m++)
#pragma unroll
        for (int n = 0; n < 4; n++){ acc[m][n][0]=0.f; acc[m][n][1]=0.f; acc[m][n][2]=0.f; acc[m][n][3]=0.f; }

    __builtin_amdgcn_s_setprio(1);
    gemm_pass(mlds, WT, nt0, w, l, lg, li, acc);
    __builtin_amdgcn_s_setprio(0);

    float cwp[4] = {0.f, 0.f, 0.f, 0.f};
#pragma unroll
    for (int mtl = 0; mtl < 2; mtl++){
        int cb = (w * 2 + mtl) * 16 + lg * 4;
        float4 bc = *(const float4*)&bc1[cb];
        float4 wc = *(const float4*)&Wc2[cb];
#pragma unroll
        for (int n = 0; n < 4; n++){
            f32x4 a = acc[mtl][n];
            cwp[n] += silu_f(a[0] + bc.x) * wc.x + silu_f(a[1] + bc.y) * wc.y
                    + silu_f(a[2] + bc.z) * wc.z + silu_f(a[3] + bc.w) * wc.w;
        }
    }
#pragma unroll
    for (int n = 0; n < 4; n++){
        float v = cwp[n];
        v += __shfl_xor(v, 16);
        v += __shfl_xor(v, 32);
        if (lg == 0) cwrow[(nt0 + n) * 16 + li] = v;
    }
}

// ---------------------------------------------------------------------------
// Fused edge + node kernel. 8 nodes / 128 edges per block, 256 threads.
// LDS exactly 40960 B, acc split to 32 AGPR/pass -> 4 blocks/CU.
// ---------------------------------------------------------------------------
__global__ __launch_bounds__(256, 4) void egnn_fused(
    const float* __restrict__ h, const float* __restrict__ x,
    const int* __restrict__ edge_idx,
    const ushort* __restrict__ A, const ushort* __restrict__ Bm,
    const float* __restrict__ We1,
    const ushort* __restrict__ We2T, const float* __restrict__ be2,
    const ushort* __restrict__ Wc1T, const float* __restrict__ bc1,
    const float* __restrict__ Wc2,
    const ushort* __restrict__ Wn1T, const float* __restrict__ bn1,
    const ushort* __restrict__ Wn2T, const float* __restrict__ bn2,
    float* __restrict__ out, int BN)
{
    // m_lds: t, then m; bytes [0,4096) reused as u (16x128 bf16) after GEMM2 reads
    __shared__ __align__(16) ushort m_lds[EB * 128];   // 32768
    __shared__ __align__(16) uint   AshCw[512];        // 2048: Ash (bf16 8x128) -> cwvp[4][128] f32
    __shared__ __align__(16) ushort hsh_bf[NB * HS];   // 2176
    __shared__ __align__(16) ushort msum_bf[NB * HS];  // 2176
    __shared__ __align__(16) ushort w256sh[128];       // 256
    __shared__ float  sqd[EB];                         // 512
    __shared__ ushort xdb[EB * 3];                     // 768
    __shared__ ushort jgs[EB];                         // 256  => total 40960

    ushort* Ash = (ushort*)AshCw;
    float (*cwvp)[EB] = (float(*)[EB])AshCw;

    const int tid = threadIdx.x;
    const int w = tid >> 6, l = tid & 63, lg = l >> 4, li = l & 15;
    const int i0 = blockIdx.x * NB;

    // ---- P0: stage h(bf16), A, w256, geometry ----
    {
        int r = tid >> 5, c = (tid & 31) * 4;
        float4 hv = *(const float4*)&h[(size_t)(i0 + r) * 128 + c];
        *(uint2*)&hsh_bf[r * HS + c] = make_uint2(pk2(hv.x, hv.y), pk2(hv.z, hv.w));
        if (tid < 128){
            int rr = tid >> 4, cc = (tid & 15) * 8;
            *(uint4*)&Ash[rr * 128 + cc] = *(const uint4*)&A[(size_t)(i0 + rr) * 128 + cc];
        } else {
            int t2 = tid - 128;
            w256sh[t2] = f2b1(We1[256 * 128 + t2]);
        }
        if (tid < EB){
            int e = tid;
            int i = i0 + (e >> 4);
            int b = i / NN;
            int jl = edge_idx[(size_t)i * KN + (e & 15)];
            int j = b * NN + jl;
            jgs[e] = (ushort)j;
            float d0 = x[(size_t)i*3+0] - x[(size_t)j*3+0];
            float d1 = x[(size_t)i*3+1] - x[(size_t)j*3+1];
            float d2 = x[(size_t)i*3+2] - x[(size_t)j*3+2];
            xdb[e*3+0] = f2b1(d0); xdb[e*3+1] = f2b1(d1); xdb[e*3+2] = f2b1(d2);
            sqd[e] = d0*d0 + d1*d1 + d2*d2;
        }
    }
    __syncthreads();

    // ---- P1: t = silu(A[i] + Bm[j] + sqd*We1[256]) -> m_lds (bf16, swizzled) ----
    {
        const int e0 = w * 32;
#pragma unroll
        for (int nt = 0; nt < 2; nt++){
            int edge = e0 + nt * 16 + li;
            int nodel = edge >> 4;
            int j = jgs[edge];
            float sq = sqd[edge];
#pragma unroll
            for (int kt = 0; kt < 4; kt++){
                int c8 = kt * 32 + lg * 8;
                uint4 ub = *(const uint4*)&Bm[(size_t)j * 128 + c8];
                uint4 ua = *(const uint4*)&Ash[nodel * 128 + c8];
                uint4 uw = *(const uint4*)&w256sh[c8];
                uint ov[4];
                const uint* pa = (const uint*)&ua;
                const uint* pb = (const uint*)&ub;
                const uint* pw = (const uint*)&uw;
#pragma unroll
                for (int p = 0; p < 4; p++){
                    float tlo = fmaf(sq, u2f_lo(pw[p]), u2f_lo(pa[p]) + u2f_lo(pb[p]));
                    float thi = fmaf(sq, u2f_hi(pw[p]), u2f_hi(pa[p]) + u2f_hi(pb[p]));
                    ov[p] = pk2(silu_f(tlo), silu_f(thi));
                }
                int blk = (kt * 4 + lg) ^ (edge & 7);
                *(uint4*)&m_lds[edge * 128 + blk * 8] = make_uint4(ov[0], ov[1], ov[2], ov[3]);
            }
        }
    }
    __syncthreads();   // [1] t complete

    // ---- GEMM1 pass A: edges 0..63 ----
    {
        f32x4 acc[2][4];
#pragma unroll
        for (int m = 0; m < 2; m++)
#pragma unroll
            for (int n = 0; n < 4; n++){ acc[m][n][0]=0.f; acc[m][n][1]=0.f; acc[m][n][2]=0.f; acc[m][n][3]=0.f; }
        __builtin_amdgcn_s_setprio(1);
        gemm_pass(m_lds, We2T, 0, w, l, lg, li, acc);
        __builtin_amdgcn_s_setprio(0);
        __syncthreads();   // [2] all waves done reading t rows 0..63
        m_epi(m_lds, be2, 0, w, lg, li, acc);   // write m rows 0..63 (own cols)
    }
    // ---- GEMM1 pass B: edges 64..127 (t rows 64..127 untouched by epi A) ----
    {
        f32x4 acc[2][4];
#pragma unroll
        for (int m = 0; m < 2; m++)
#pragma unroll
            for (int n = 0; n < 4; n++){ acc[m][n][0]=0.f; acc[m][n][1]=0.f; acc[m][n][2]=0.f; acc[m][n][3]=0.f; }
        __builtin_amdgcn_s_setprio(1);
        gemm_pass(m_lds, We2T, 4, w, l, lg, li, acc);
        __builtin_amdgcn_s_setprio(0);
        __syncthreads();   // [3] all waves done reading t rows 64..127
        m_epi(m_lds, be2, 4, w, lg, li, acc);   // write m rows 64..127 (own cols)
    }

    // ---- msum: own cols, all nodes; staggered k to avoid bank conflicts ----
    {
        int nodel = l >> 3;
        int c0 = w * 32 + (l & 7) * 4;
        float s0=0.f, s1=0.f, s2=0.f, s3=0.f;
#pragma unroll
        for (int s = 0; s < 16; s++){
            int k = (s + nodel) & 15;
            int edge = nodel * 16 + k;
            int blk = (c0 >> 3) ^ (edge & 7);
            uint2 v = *(const uint2*)&m_lds[edge * 128 + blk * 8 + (c0 & 4)];
            s0 += u2f_lo(v.x); s1 += u2f_hi(v.x);
            s2 += u2f_lo(v.y); s3 += u2f_hi(v.y);
        }
        *(uint2*)&msum_bf[nodel * HS + c0] = make_uint2(pk2(s0, s1), pk2(s2, s3));
    }
    __syncthreads();   // [4] m + msum complete

    // ---- GEMM2 (two passes, read-only): cw = Wc2 . silu(m@Wc1+bc1) ----
    gemm2_pass(m_lds, Wc1T, bc1, Wc2, cwvp[w], 0, w, l, lg, li);
    gemm2_pass(m_lds, Wc1T, bc1, Wc2, cwvp[w], 4, w, l, lg, li);
    __syncthreads();   // [5] all waves done reading m; cwv ready

    // ---- GEMM3: u = silu([h|msum]@Wn1+bn1) -> m_lds rows 0..15 ----
    {
        f32x4 acc3[2];
        acc3[0][0]=0.f; acc3[0][1]=0.f; acc3[0][2]=0.f; acc3[0][3]=0.f;
        acc3[1][0]=0.f; acc3[1][1]=0.f; acc3[1][2]=0.f; acc3[1][3]=0.f;
        int node = li & 7;
#pragma unroll
        for (int kt = 0; kt < 8; kt++){
            const ushort* bp = (kt < 4) ? &hsh_bf[node * HS + kt * 32 + lg * 8]
                                        : &msum_bf[node * HS + (kt - 4) * 32 + lg * 8];
            s16x8 bf = *(const s16x8*)bp;
#pragma unroll
            for (int mtl = 0; mtl < 2; mtl++){
                int mt = w * 2 + mtl;
                s16x8 af = *(const s16x8*)&Wn1T[(size_t)(mt * 8 + kt) * 512 + l * 8];
                acc3[mtl] = __builtin_amdgcn_mfma_f32_16x16x32_bf16(af, bf, acc3[mtl], 0, 0, 0);
            }
        }
#pragma unroll
        for (int mtl = 0; mtl < 2; mtl++){
            int mt = w * 2 + mtl;
            int cb = mt * 16 + lg * 4;
            float4 bb = *(const float4*)&bn1[cb];
            uint o01 = 0, o23 = 0;
            if (li < 8){
                f32x4 a = acc3[mtl];
                o01 = pk2(silu_f(a[0] + bb.x), silu_f(a[1] + bb.y));
                o23 = pk2(silu_f(a[2] + bb.z), silu_f(a[3] + bb.w));
            }
            int blk = (mt * 2 + (lg >> 1)) ^ (li & 7);
            *(uint2*)&m_lds[li * 128 + blk * 8 + (lg & 1) * 4] = make_uint2(o01, o23);
        }
    }
    __syncthreads();   // [6] u complete

    // ---- x update: xdb (bf16, staged once) * cwv ----
    if (tid < 24){
        int nd = tid / 3, d = tid % 3;
        int i = i0 + nd;
        float s = 0.f;
#pragma unroll
        for (int k = 0; k < 16; k++){
            int e = nd * 16 + k;
            float cw = cwvp[0][e] + cwvp[1][e] + cwvp[2][e] + cwvp[3][e];
            s += b2f(xdb[e * 3 + d]) * cw;
        }
        out[(size_t)BN * H + (size_t)i * 3 + d] = x[(size_t)i * 3 + d] + s * (1.0f / 16.0f);
    }

    // ---- GEMM4: h_new = u@Wn2 + bn2 + h (residual from hsh_bf) ----
    {
        f32x4 acc4[2];
        acc4[0][0]=0.f; acc4[0][1]=0.f; acc4[0][2]=0.f; acc4[0][3]=0.f;
        acc4[1][0]=0.f; acc4[1][1]=0.f; acc4[1][2]=0.f; acc4[1][3]=0.f;
#pragma unroll
        for (int kt = 0; kt < 4; kt++){
            int blk = (kt * 4 + lg) ^ (li & 7);
            s16x8 bf = *(const s16x8*)&m_lds[li * 128 + blk * 8];
#pragma unroll
            for (int mtl = 0; mtl < 2; mtl++){
                int mt = w * 2 + mtl;
                s16x8 af = *(const s16x8*)&Wn2T[(size_t)(mt * 4 + kt) * 512 + l * 8];
                acc4[mtl] = __builtin_amdgcn_mfma_f32_16x16x32_bf16(af, bf, acc4[mtl], 0, 0, 0);
            }
        }
#pragma unroll
        for (int mtl = 0; mtl < 2; mtl++){
            int mt = w * 2 + mtl;
            int cb = mt * 16 + lg * 4;
            if (li < 8){
                float4 bb = *(const float4*)&bn2[cb];
                uint2 hu = *(const uint2*)&hsh_bf[li * HS + cb];
                f32x4 a = acc4[mtl];
                float4 o;
                o.x = a[0] + bb.x + u2f_lo(hu.x);
                o.y = a[1] + bb.y + u2f_hi(hu.x);
                o.z = a[2] + bb.z + u2f_lo(hu.y);
                o.w = a[3] + bb.w + u2f_hi(hu.y);
                *(float4*)&out[(size_t)(i0 + li) * 128 + cb] = o;
            }
        }
    }
}

extern "C" void kernel_launch(void* const* d_in, const int* in_sizes, int n_in,
                              void* d_out, int out_size, void* d_ws, size_t ws_size,
                              hipStream_t stream) {
    const float* h        = (const float*)d_in[0];
    const float* x        = (const float*)d_in[1];
    const int*   edge_idx = (const int*)d_in[2];
    const float* We1      = (const float*)d_in[3];
    const float* be1      = (const float*)d_in[4];
    const float* We2      = (const float*)d_in[5];
    const float* be2      = (const float*)d_in[6];
    const float* Wc1      = (const float*)d_in[7];
    const float* bc1      = (const float*)d_in[8];
    const float* Wc2      = (const float*)d_in[9];
    const float* Wn1      = (const float*)d_in[10];
    const float* bn1      = (const float*)d_in[11];
    const float* Wn2      = (const float*)d_in[12];
    const float* bn2      = (const float*)d_in[13];
    float* out = (float*)d_out;

    const int BN = in_sizes[0] / H;   // 32768

    ushort* A    = (ushort*)d_ws;
    ushort* Bm   = A + (size_t)BN * H;
    ushort* We2T = Bm + (size_t)BN * H;
    ushort* Wc1T = We2T + 32 * 512;
    ushort* Wn1T = Wc1T + 32 * 512;
    ushort* Wn2T = Wn1T + 64 * 512;
    ushort* W1pT = Wn2T + 32 * 512;

    pack_all<<<56, 256, 0, stream>>>(We2, Wc1, Wn1, Wn2, We1,
                                     We2T, Wc1T, Wn1T, Wn2T, W1pT);
    precompute_mfma<<<BN / 64, 256, 0, stream>>>(h, be1, W1pT, A, Bm);
    egnn_fused<<<BN / NB, 256, 0, stream>>>(h, x, edge_idx, A, Bm, We1,
                                            We2T, be2, Wc1T, bc1, Wc2,
                                            Wn1T, bn1, Wn2T, bn2, out, BN);
}